// Round 8
// baseline (207.936 us; speedup 1.0000x reference)
//
#include <hip/hip_runtime.h>

#define DIM   64
#define NEMB  1024
#define HW    4096      // 64*64
#define NPIX  131072    // 32*64*64
#define NOUT  8388608   // 32*64*64*64
#define TILE  128       // pixels per block (R7: 256 -> 76KB LDS -> 2 blk/CU; 128 -> 39KB -> 4 blk/CU)
#define JC    16        // codes per register tile
#define CPS   256       // codes per wave (4 waves cover 1024)

// ---------------------------------------------------------------------------
// prep: cn[j] = ||e_j||^2, numpy axis-0 semantics (rounded muls, sequential
// adds). Scan consumes embed[d][j] directly (contiguous in j -> s_load).
// ---------------------------------------------------------------------------
__global__ __launch_bounds__(256) void prep_kernel(const float* __restrict__ embed,
                                                   float* __restrict__ cn) {
    const int j = blockIdx.x * 256 + threadIdx.x;
    if (j >= NEMB) return;
    float v = embed[j];
    float s = __fmul_rn(v, v);
#pragma unroll
    for (int d = 1; d < DIM; ++d) {
        v = embed[d * NEMB + j];
        s = __fadd_rn(s, __fmul_rn(v, v));
    }
    cn[j] = s;
}

// ---------------------------------------------------------------------------
// fused VQ kernel. x staged in LDS (R2-R5: regalloc never keeps x resident in
// VGPRs; LDS it cannot defeat). TILE=128 keeps the block at ~39KB LDS so 4
// blocks/CU co-reside (R6 at 76KB had only 2 -> VALUBusy 65%). 4 waves x
// 256-code ranges; lane owns 2 pixels x 16 codes (acc[2][16], static idx).
// Distance arithmetic identical to the R0-passing kernel; packed-u64 min
// merge = exact first-occurrence argmin.
// ---------------------------------------------------------------------------
__global__ __launch_bounds__(256)
__attribute__((amdgpu_waves_per_eu(4, 4)))
void vq_kernel(const float* __restrict__ X,
               const float* __restrict__ embed,
               const float* __restrict__ cn,
               float* __restrict__ OUT,
               float* __restrict__ loss) {
    __shared__ float x_lds[DIM][TILE];            // 32 KB
    __shared__ float ff_lds[TILE];                // 512 B
    __shared__ unsigned long long sm[4 * TILE];   // 4 KB
    __shared__ int   idx_lds[TILE];               // 512 B
    __shared__ float sred[256];                   // 1 KB

    const int tid  = threadIdx.x;
    const int l    = tid & 63;
    const int w    = tid >> 6;
    const int pix0 = blockIdx.x * TILE;
    const int b    = pix0 >> 12;        // 128 | 4096 -> same image per block
    const int p0   = pix0 & 4095;

    // ---- stage: threads 0..127 own pixel tid; load 64 d-values (coalesced
    //      across lanes per d), write LDS, compute ||f||^2 with the numpy
    //      pairwise-8 pattern from the register copies (bitwise == R6).
    if (tid < TILE) {
        const float* xb = X + (size_t)b * (DIM * HW) + p0 + tid;
        float rr[8];
#pragma unroll
        for (int i = 0; i < 8; ++i) {
            const float v = xb[(size_t)i * HW];
            x_lds[i][tid] = v;
            rr[i] = __fmul_rn(v, v);
        }
#pragma unroll
        for (int i = 8; i < DIM; i += 8)
#pragma unroll
            for (int q = 0; q < 8; ++q) {
                const float v = xb[(size_t)(i + q) * HW];
                x_lds[i + q][tid] = v;
                rr[q] = __fadd_rn(rr[q], __fmul_rn(v, v));
            }
        ff_lds[tid] = __fadd_rn(
            __fadd_rn(__fadd_rn(rr[0], rr[1]), __fadd_rn(rr[2], rr[3])),
            __fadd_rn(__fadd_rn(rr[4], rr[5]), __fadd_rn(rr[6], rr[7])));
    }
    __syncthreads();

    // ---- scan: wave w covers codes [w*CPS, w*CPS+CPS) for pixels 2l, 2l+1
    const int jbase = __builtin_amdgcn_readfirstlane(w * CPS);  // manifest-scalar
    const float ffa = ff_lds[2 * l];
    const float ffb = ff_lds[2 * l + 1];

    float minva = __builtin_inff(), minvb = __builtin_inff();
    int   minia = 0, minib = 0;

#pragma unroll 1
    for (int g = 0; g < CPS / JC; ++g) {
        const int j0 = jbase + g * JC;
        float acca[JC], accb[JC];
#pragma unroll
        for (int c = 0; c < JC; ++c) { acca[c] = 0.f; accb[c] = 0.f; }

        const float* erow = embed + j0;     // scalar base
#pragma unroll 4
        for (int d = 0; d < DIM; ++d) {
            const float2 x2 = *reinterpret_cast<const float2*>(&x_lds[d][2 * l]);
#pragma unroll
            for (int c = 0; c < JC; ++c) {
                const float ev = erow[(size_t)d * NEMB + c];   // s_load, 16 contiguous
                acca[c] = fmaf(x2.x, ev, acca[c]);   // sequential-d chain per
                accb[c] = fmaf(x2.y, ev, accb[c]);   // (pix,code) == R0 order
            }
        }
#pragma unroll
        for (int c = 0; c < JC; ++c) {
            const float cnj = cn[j0 + c];
            const float da = __fadd_rn(__fsub_rn(ffa, __fmul_rn(2.f, acca[c])), cnj);
            const float db = __fadd_rn(__fsub_rn(ffb, __fmul_rn(2.f, accb[c])), cnj);
            if (da < minva) { minva = da; minia = j0 + c; }   // strict <
            if (db < minvb) { minvb = db; minib = j0 + c; }
        }
    }

    sm[w * TILE + 2 * l] =
        ((unsigned long long)__float_as_uint(minva) << 32) | (unsigned)minia;
    sm[w * TILE + 2 * l + 1] =
        ((unsigned long long)__float_as_uint(minvb) << 32) | (unsigned)minib;
    __syncthreads();

    // ---- merge 4 waves (dist>0 -> bit order valid; low-32 idx -> exact
    //      ties pick the smaller index = np.argmin first occurrence)
    if (tid < TILE) {
        unsigned long long m = sm[tid];
#pragma unroll
        for (int s = 1; s < 4; ++s) {
            const unsigned long long c2 = sm[s * TILE + tid];
            m = (c2 < m) ? c2 : m;
        }
        idx_lds[tid] = (int)(m & 0xFFFFFFFFull);
    }
    __syncthreads();

    // ---- output + loss: thread t -> pixel t&127, d-half t>>7. x from LDS,
    //      embed gather L2-resident (256 KB), writes coalesced across pix.
    const int pixe = tid & (TILE - 1);
    const int dh   = tid >> 7;            // 0 or 1 -> d in [32dh, 32dh+32)
    const int idx  = idx_lds[pixe];
    float lerr = 0.f;
    float* outb = OUT + (size_t)b * (DIM * HW) + p0 + pixe;
#pragma unroll 8
    for (int k = 0; k < DIM / 2; ++k) {
        const int d = dh * (DIM / 2) + k;
        const float qv = embed[d * NEMB + idx];
        const float xv = x_lds[d][pixe];
        const float df = __fsub_rn(qv, xv);
        outb[(size_t)d * HW] = __fadd_rn(xv, df);
        lerr = fmaf(df, df, lerr);
    }

    sred[tid] = lerr;
    __syncthreads();
#pragma unroll
    for (int s = 128; s > 0; s >>= 1) {
        if (tid < s) sred[tid] += sred[tid + s];
        __syncthreads();
    }
    if (tid == 0)
        atomicAdd(loss, sred[0] * (1.0f / (float)NOUT));
}

extern "C" void kernel_launch(void* const* d_in, const int* in_sizes, int n_in,
                              void* d_out, int out_size, void* d_ws, size_t ws_size,
                              hipStream_t stream) {
    const float* X = (const float*)d_in[0];
    const float* E = (const float*)d_in[1];
    float* OUT  = (float*)d_out;
    float* loss = OUT + NOUT;
    float* cn   = (float*)d_ws;    // 1024 floats

    hipMemsetAsync(loss, 0, sizeof(float), stream);
    prep_kernel<<<NEMB / 256, 256, 0, stream>>>(E, cn);
    vq_kernel<<<NPIX / TILE, 256, 0, stream>>>(X, E, cn, OUT, loss);
}